// Round 4
// baseline (945.387 us; speedup 1.0000x reference)
//
#include <hip/hip_runtime.h>
#include <cmath>

constexpr int T_TOK = 8192;   // B*S
constexpr int DM    = 1024;   // d
constexpr int FF    = 4096;   // f
constexpr int NE    = 8;      // experts
constexpr int KTOP  = 2;
constexpr int CAP   = 2560;   // ceil(1.25 * T*K / E)
constexpr int NCHUNK = (T_TOK * KTOP) / 256;   // 64 chunks for the FCFS scan

typedef _Float16 f16x8  __attribute__((ext_vector_type(8)));
typedef float    f32x16 __attribute__((ext_vector_type(16)));

__device__ __forceinline__ void glds16(const void* g, void* l) {
  __builtin_amdgcn_global_load_lds(
      (const __attribute__((address_space(1))) unsigned int*)g,
      (__attribute__((address_space(3))) unsigned int*)l, 16, 0, 0);
}

// tanh-form GELU: one v_exp_f32, overflow-safe (t=inf -> th=1), max dev ~2e-4
__device__ __forceinline__ float fast_gelu(float v) {
  float u = v * (0.7978845608f + 0.0356774081f * v * v);
  float t = __expf(2.0f * u);
  float th = 1.0f - 2.0f / (t + 1.0f);
  return 0.5f * v * (1.0f + th);
}

// ---------------- router: fp64 logits/softmax/top-2, one wave per token ----------------
__global__ __launch_bounds__(256) void router_kernel(
    const float* __restrict__ x, const float* __restrict__ Wr,
    const float* __restrict__ br, int* __restrict__ topk_e, float* __restrict__ topk_w)
{
  int wave = threadIdx.x >> 6, lane = threadIdx.x & 63;
  int t = blockIdx.x * 4 + wave;
  const float4* xr4 = (const float4*)(x + (size_t)t * DM);
  double acc[NE];
#pragma unroll
  for (int e = 0; e < NE; ++e) acc[e] = 0.0;
#pragma unroll
  for (int it = 0; it < DM / 4 / 64; ++it) {
    int j4 = it * 64 + lane;
    float4 xv = xr4[j4];
    const float* wr = Wr + (size_t)j4 * 4 * NE;
    float xs[4] = {xv.x, xv.y, xv.z, xv.w};
#pragma unroll
    for (int s = 0; s < 4; ++s) {
      double xd = (double)xs[s];
#pragma unroll
      for (int e = 0; e < NE; ++e) acc[e] += xd * (double)wr[s * NE + e];
    }
  }
#pragma unroll
  for (int off = 32; off >= 1; off >>= 1) {
#pragma unroll
    for (int e = 0; e < NE; ++e) acc[e] += __shfl_down(acc[e], off, 64);
  }
  if (lane == 0) {
    double mx = -1e300;
#pragma unroll
    for (int e = 0; e < NE; ++e) { acc[e] += (double)br[e]; if (acc[e] > mx) mx = acc[e]; }
    double p[NE]; double s = 0.0;
#pragma unroll
    for (int e = 0; e < NE; ++e) { p[e] = exp(acc[e] - mx); s += p[e]; }
#pragma unroll
    for (int e = 0; e < NE; ++e) p[e] /= s;
    int e1 = 0;
    for (int e = 1; e < NE; ++e) if (p[e] > p[e1]) e1 = e;           // ties -> lowest idx
    int e2 = (e1 == 0) ? 1 : 0;
    for (int e = 0; e < NE; ++e) { if (e == e1) continue; if (p[e] > p[e2]) e2 = e; }
    double wsum = p[e1] + p[e2]; if (wsum < 1e-9) wsum = 1e-9;
    topk_e[t*2+0] = e1; topk_e[t*2+1] = e2;
    topk_w[t*2+0] = (float)(p[e1] / wsum);
    topk_w[t*2+1] = (float)(p[e2] / wsum);
  }
}

// ---------------- FCFS capacity scan, parallel 3-phase ----------------
__global__ __launch_bounds__(256) void hist_kernel(
    const int* __restrict__ topk_e, int* __restrict__ hist)   // hist[NCHUNK][NE]
{
  __shared__ int wcnt[4][NE];
  int tid = threadIdx.x, lane = tid & 63, wave = tid >> 6;
  int e = topk_e[blockIdx.x * 256 + tid];
#pragma unroll
  for (int ee = 0; ee < NE; ++ee) {
    unsigned long long m = __ballot(e == ee);
    if (lane == 0) wcnt[wave][ee] = __popcll(m);
  }
  __syncthreads();
  if (tid < NE)
    hist[blockIdx.x * NE + tid] = wcnt[0][tid] + wcnt[1][tid] + wcnt[2][tid] + wcnt[3][tid];
}

__global__ __launch_bounds__(64) void prefix_kernel(
    const int* __restrict__ hist, int* __restrict__ base, int* __restrict__ counts)
{
  int e = threadIdx.x;
  if (e >= NE) return;
  int h[NCHUNK];
#pragma unroll
  for (int c = 0; c < NCHUNK; ++c) h[c] = hist[c * NE + e];
  int b = 0;
#pragma unroll
  for (int c = 0; c < NCHUNK; ++c) { base[c * NE + e] = b; b += h[c]; }
  counts[e] = b < CAP ? b : CAP;
}

__global__ __launch_bounds__(256) void assign_kernel(
    const int* __restrict__ topk_e, const int* __restrict__ base,
    int* __restrict__ assign_slot, int* __restrict__ slot_token)
{
  __shared__ int wcnt[4][NE];
  __shared__ int woff[4][NE];
  int tid = threadIdx.x, lane = tid & 63, wave = tid >> 6;
  int gi = blockIdx.x * 256 + tid;
  int e = topk_e[gi];
  int rank = 0;
  unsigned long long lt = (1ull << lane) - 1ull;
#pragma unroll
  for (int ee = 0; ee < NE; ++ee) {
    unsigned long long m = __ballot(e == ee);
    if (e == ee) rank = __popcll(m & lt);
    if (lane == 0) wcnt[wave][ee] = __popcll(m);
  }
  __syncthreads();
  if (tid < NE) {
    int b = base[blockIdx.x * NE + tid];
#pragma unroll
    for (int w = 0; w < 4; ++w) { woff[w][tid] = b; b += wcnt[w][tid]; }
  }
  __syncthreads();
  int pos = woff[wave][e] + rank;
  bool keep = pos < CAP;
  assign_slot[gi] = keep ? (e * CAP + pos) : -1;
  if (keep) slot_token[e * CAP + pos] = gi >> 1;   // K=2
}

// ---------------- fp32 [E][R][C] -> fp16 [E][C][R], 64x64 tiles, 16B I/O both sides ----------------
__global__ __launch_bounds__(256) void transpose_f16(
    const float* __restrict__ in, _Float16* __restrict__ out, int R, int C)
{
  __shared__ float tile[64][65];
  size_t eoff = (size_t)blockIdx.z * R * C;
  const float* src = in + eoff;
  _Float16* dst = out + eoff;
  int r0 = blockIdx.y * 64, c0 = blockIdx.x * 64;
  int t = threadIdx.x;
  int rr = t >> 4, cc = (t & 15) * 4;          // 16 in-rows per pass, float4 each
#pragma unroll
  for (int i = 0; i < 4; ++i) {
    float4 v = *(const float4*)(src + (size_t)(r0 + rr + i*16) * C + (c0 + cc));
    tile[rr + i*16][cc + 0] = v.x; tile[rr + i*16][cc + 1] = v.y;
    tile[rr + i*16][cc + 2] = v.z; tile[rr + i*16][cc + 3] = v.w;
  }
  __syncthreads();
  int oc = t >> 3, orr = (t & 7) * 8;          // 32 out-rows per pass, 8 fp16 each
#pragma unroll
  for (int i = 0; i < 2; ++i) {
    int c = oc + i * 32;
    _Float16 tmp[8];
#pragma unroll
    for (int j = 0; j < 8; ++j) tmp[j] = (_Float16)tile[orr + j][c];
    *(uint4*)(dst + (size_t)(c0 + c) * R + (r0 + orr)) = *(uint4*)tmp;
  }
}

// ---------------- gather kept tokens into [E][CAP][d] fp16 ----------------
__global__ __launch_bounds__(256) void gather_kernel(
    const float* __restrict__ x, const int* __restrict__ slot_token,
    const int* __restrict__ counts, _Float16* __restrict__ xbuf)
{
  int p = blockIdx.x, e = blockIdx.y;
  if (p >= counts[e]) return;
  int tkn = slot_token[e * CAP + p];
  float4 v = ((const float4*)(x + (size_t)tkn * DM))[threadIdx.x];
  _Float16 tmp[4] = {(_Float16)v.x, (_Float16)v.y, (_Float16)v.z, (_Float16)v.w};
  uint2 bits; __builtin_memcpy(&bits, tmp, 8);
  ((uint2*)(xbuf + ((size_t)e * CAP + p) * DM))[threadIdx.x] = bits;
}

// ---------------- 256x256 fp16 MFMA GEMM, BK=32, 4-deep LDS pipeline ----------------
// A: [NE][CAP][K], Bt: [NE][N][K], C: [NE][CAP][N]; tiles past counts[e] early-exit.
// 512 threads = 8 waves (2M x 4N), per-wave output 128x64 (4x2 32x32 frags).
// LDS: 4 circular buffers x (A 256x32 + B 256x32) f16 = 128 KB, 1 block/CU.
// Pipeline (T3+T4): iter t = { stage(t+3); vmcnt(12); barrier; 12 ds_read frags;
// setprio(1); 16 MFMA; setprio(0); barrier }. vmcnt NEVER drains to 0 in steady
// state (12 = 3 tiles x 4 loads in flight). Race-freedom: stage of buf[(t+3)&3]
// issues after barrier2(t-1), whose previous occupant (t-1) was fully read
// (lgkm0 before its MFMAs) before that barrier; reads of tile t protected by
// per-wave vmcnt(12) (in-order retirement) + barrier.
// Swizzle: LDS[r][c16] = G[r][c16 ^ ((r^(r>>2))&3)], inverted on ds_read (4-way
// residual bank aliasing, same rate as prior kernel).
// T1: bijective XCD remap, bx innermost. KSPLIT=2: upper by-half computes
// k in [K/2,K), partial (no bias) to Cout1.
template <bool GELU, bool OUTF16, int KSPLIT>
__global__ __launch_bounds__(512, 2) void gemm256(
    const _Float16* __restrict__ A, const _Float16* __restrict__ Bt,
    const float* __restrict__ bias, void* __restrict__ Cout, void* __restrict__ Cout1,
    const int* __restrict__ counts, int K, int N)
{
  constexpr int BM = 256, BN = 256, BK = 32;
  __shared__ _Float16 As[4][BM * BK];   // 4 x 16KB
  __shared__ _Float16 Bs[4][BN * BK];

  // ---- XCD-aware bijective remap (grid products here are multiples of 8) ----
  int nx = gridDim.x, ny = gridDim.y;
  int w = blockIdx.x + nx * (blockIdx.y + ny * blockIdx.z);
  int nwg = nx * ny * (int)gridDim.z;
  int q = nwg >> 3, r = nwg & 7;
  int xcd = w & 7, idx = w >> 3;
  int L = (xcd < r ? xcd * (q + 1) : r * (q + 1) + (xcd - r) * q) + idx;
  int bx = L % nx; int t1 = L / nx; int by = t1 % ny; int e = t1 / ny;

  int Me = counts[e];
  int split = 0;
  if constexpr (KSPLIT == 2) {
    int nyt = ny >> 1;
    split = by >= nyt;
    if (split) by -= nyt;
  }
  int m0 = by * BM;
  if (m0 >= Me) return;               // capacity padding: skip empty tiles (block-uniform)
  int kbeg = 0, kend = K;
  if constexpr (KSPLIT == 2) { int kh = K >> 1; kbeg = split * kh; kend = kbeg + kh; }

  int tid = threadIdx.x, lane = tid & 63, wave = tid >> 6;
  int wm = wave >> 2, wn = wave & 3;           // 2 x 4 waves; wave out 128x64
  const _Float16* Ae = A + ((size_t)e * CAP + m0) * K;
  const _Float16* Be = Bt + ((size_t)e * N + (size_t)bx * BN) * K;
  int n31 = lane & 31, khalf = lane >> 5;
  int srow = lane >> 2, scol = lane & 3;       // staging lane map: 16 rows x 4 chunks / wave
  int sw4 = (n31 ^ (n31 >> 2)) & 3;            // read-side swizzle (row bits fold to n31 bits)

  f32x16 acc[4][2] = {};

  auto stage = [&](int t) {
    int b = t & 3;
    int k0 = kbeg + t * BK;
#pragma unroll
    for (int l = 0; l < 2; ++l) {
      int row = l * 128 + wave * 16 + srow;
      int csw = scol ^ ((row ^ (row >> 2)) & 3);
      glds16(Ae + (size_t)row * K + (k0 + csw * 8), (char*)&As[b][0] + (l * 8192 + wave * 1024));
      glds16(Be + (size_t)row * K + (k0 + csw * 8), (char*)&Bs[b][0] + (l * 8192 + wave * 1024));
    }
  };

  auto compute = [&](int t) {
    const _Float16* Ab = &As[t & 3][0] + (size_t)(wm * 128 + n31) * BK;
    const _Float16* Bb = &Bs[t & 3][0] + (size_t)(wn * 64 + n31) * BK;
    f16x8 a[2][4], bf[2][2];
#pragma unroll
    for (int kk = 0; kk < 2; ++kk) {
      int ck = kk * 2 + khalf;                 // logical 16B chunk 0..3
      int coff = ((ck ^ sw4) << 3);            // swizzled element offset
#pragma unroll
      for (int mi = 0; mi < 4; ++mi) a[kk][mi] = *(const f16x8*)(Ab + mi * 32 * BK + coff);
#pragma unroll
      for (int ni = 0; ni < 2; ++ni) bf[kk][ni] = *(const f16x8*)(Bb + ni * 32 * BK + coff);
    }
    __builtin_amdgcn_s_setprio(1);
#pragma unroll
    for (int kk = 0; kk < 2; ++kk)
#pragma unroll
      for (int mi = 0; mi < 4; ++mi)
#pragma unroll
        for (int ni = 0; ni < 2; ++ni)
          acc[mi][ni] = __builtin_amdgcn_mfma_f32_32x32x16_f16(a[kk][mi], bf[kk][ni], acc[mi][ni], 0, 0, 0);
    __builtin_amdgcn_s_setprio(0);
  };

#define FENCE asm volatile("" ::: "memory")
#define BAR   do { FENCE; __builtin_amdgcn_s_barrier(); FENCE; } while (0)

  int nk = (kend - kbeg) / BK;                 // 32 (GEMM1) or 64 (GEMM2 half-K)
  stage(0); stage(1); stage(2);
  int t = 0;
  for (; t < nk - 3; ++t) {
    stage(t + 3);
    asm volatile("s_waitcnt vmcnt(12)" ::: "memory");
    BAR;
    compute(t);
    BAR;
  }
  asm volatile("s_waitcnt vmcnt(8)" ::: "memory");
  BAR; compute(t); ++t; BAR;
  asm volatile("s_waitcnt vmcnt(4)" ::: "memory");
  BAR; compute(t); ++t; BAR;
  asm volatile("s_waitcnt vmcnt(0)" ::: "memory");
  BAR; compute(t);

#undef BAR
#undef FENCE

  const float* be = bias + (size_t)e * N;
  float bmul = (split == 0) ? 1.0f : 0.0f;     // bias only in k-split 0
  void* outb = (split == 0) ? Cout : Cout1;
#pragma unroll
  for (int mi = 0; mi < 4; ++mi) {
#pragma unroll
    for (int reg = 0; reg < 16; ++reg) {
      int row = m0 + wm * 128 + mi * 32 + 4 * khalf + (reg & 3) + 8 * (reg >> 2);
      size_t rowoff = ((size_t)e * CAP + row) * N;
#pragma unroll
      for (int ni = 0; ni < 2; ++ni) {
        int col = bx * BN + wn * 64 + ni * 32 + n31;
        float v = acc[mi][ni][reg] + bmul * be[col];
        if constexpr (GELU) v = fast_gelu(v);
        if constexpr (OUTF16) ((_Float16*)outb)[rowoff + col] = (_Float16)v;
        else                  ((float*)outb)[rowoff + col] = v;
      }
    }
  }
}

// ---------------- combine: out[t] = sum_k w_k * (ypart0[slot_k] + ypart1[slot_k]) ----------------
__global__ __launch_bounds__(256) void combine_kernel(
    const float* __restrict__ ybuf0, const float* __restrict__ ybuf1,
    const int* __restrict__ assign_slot, const float* __restrict__ topk_w,
    float* __restrict__ out)
{
  int t = blockIdx.x;
  int s0 = assign_slot[t*2+0], s1 = assign_slot[t*2+1];
  float w0 = topk_w[t*2+0], w1 = topk_w[t*2+1];
  float4 a = {0.f, 0.f, 0.f, 0.f};
  int j = threadIdx.x;
  if (s0 >= 0) {
    float4 y = ((const float4*)(ybuf0 + (size_t)s0 * DM))[j];
    float4 z = ((const float4*)(ybuf1 + (size_t)s0 * DM))[j];
    a.x += w0*(y.x+z.x); a.y += w0*(y.y+z.y); a.z += w0*(y.z+z.z); a.w += w0*(y.w+z.w);
  }
  if (s1 >= 0) {
    float4 y = ((const float4*)(ybuf0 + (size_t)s1 * DM))[j];
    float4 z = ((const float4*)(ybuf1 + (size_t)s1 * DM))[j];
    a.x += w1*(y.x+z.x); a.y += w1*(y.y+z.y); a.z += w1*(y.z+z.z); a.w += w1*(y.w+z.w);
  }
  ((float4*)(out + (size_t)t * DM))[j] = a;
}

extern "C" void kernel_launch(void* const* d_in, const int* in_sizes, int n_in,
                              void* d_out, int out_size, void* d_ws, size_t ws_size,
                              hipStream_t stream)
{
  (void)in_sizes; (void)n_in; (void)out_size; (void)ws_size;
  const float* x  = (const float*)d_in[0];
  const float* Wr = (const float*)d_in[1];
  const float* br = (const float*)d_in[2];
  const float* W1 = (const float*)d_in[3];
  const float* b1 = (const float*)d_in[4];
  const float* W2 = (const float*)d_in[5];
  const float* b2 = (const float*)d_in[6];
  float* out = (float*)d_out;

  char* wsp = (char*)d_ws;
  size_t off = 0;
  auto take = [&](size_t bytes) { char* p = wsp + off; off += (bytes + 255) & ~(size_t)255; return p; };
  // Order matters: W1t and xbuf are adjacent (each size is 256B-aligned already)
  // so their combined 109 MB region can be reused as the 84 MB split-K partial-1
  // buffer for GEMM2 (both are dead once GEMM1 has run). Keeps ws footprint flat.
  _Float16* W2t  = (_Float16*)take((size_t)NE * DM * FF * 2);   // [E][d][f]
  _Float16* W1t  = (_Float16*)take((size_t)NE * FF * DM * 2);   // [E][f][d]
  _Float16* xbuf = (_Float16*)take((size_t)NE * CAP * DM * 2);  // [E][cap][d]
  _Float16* hbuf = (_Float16*)take((size_t)NE * CAP * FF * 2);  // [E][cap][f]
  float*    ybuf = (float*)take((size_t)NE * CAP * DM * 4);     // [E][cap][d] k-split partial 0
  float*    ybuf1 = (float*)W1t;  // k-split partial 1 aliases (dead) W1t+xbuf: 109MB >= 84MB
  int*   topk_e      = (int*)take((size_t)T_TOK * KTOP * 4);
  float* topk_w      = (float*)take((size_t)T_TOK * KTOP * 4);
  int*   assign_slot = (int*)take((size_t)T_TOK * KTOP * 4);
  int*   slot_token  = (int*)take((size_t)NE * CAP * 4);
  int*   counts      = (int*)take((size_t)NE * 4);
  int*   hist        = (int*)take((size_t)NCHUNK * NE * 4);
  int*   cbase       = (int*)take((size_t)NCHUNK * NE * 4);

  router_kernel<<<T_TOK / 4, 256, 0, stream>>>(x, Wr, br, topk_e, topk_w);
  hist_kernel<<<NCHUNK, 256, 0, stream>>>(topk_e, hist);
  prefix_kernel<<<1, 64, 0, stream>>>(hist, cbase, counts);
  assign_kernel<<<NCHUNK, 256, 0, stream>>>(topk_e, cbase, assign_slot, slot_token);
  transpose_f16<<<dim3(FF/64, DM/64, NE), 256, 0, stream>>>(W1, W1t, DM, FF);
  transpose_f16<<<dim3(DM/64, FF/64, NE), 256, 0, stream>>>(W2, W2t, FF, DM);
  gather_kernel<<<dim3(CAP, NE), 256, 0, stream>>>(x, slot_token, counts, xbuf);
  gemm256<true,  true,  1><<<dim3(FF/256, CAP/256, NE), 512, 0, stream>>>(
      xbuf, W1t, b1, (void*)hbuf, nullptr, counts, DM, FF);
  gemm256<false, false, 2><<<dim3(DM/256, (CAP/256)*2, NE), 512, 0, stream>>>(
      hbuf, W2t, b2, (void*)ybuf, (void*)ybuf1, counts, FF, DM);
  combine_kernel<<<T_TOK, 256, 0, stream>>>(ybuf, ybuf1, assign_slot, topk_w, out);
}

// Round 5
// 820.649 us; speedup vs baseline: 1.1520x; 1.1520x over previous
//
#include <hip/hip_runtime.h>
#include <cmath>

constexpr int T_TOK = 8192;   // B*S
constexpr int DM    = 1024;   // d
constexpr int FF    = 4096;   // f
constexpr int NE    = 8;      // experts
constexpr int KTOP  = 2;
constexpr int CAP   = 2560;   // ceil(1.25 * T*K / E)
constexpr int NCHUNK = (T_TOK * KTOP) / 256;   // 64 chunks for the FCFS scan

typedef _Float16 f16x8  __attribute__((ext_vector_type(8)));
typedef float    f32x16 __attribute__((ext_vector_type(16)));

__device__ __forceinline__ void glds16(const void* g, void* l) {
  __builtin_amdgcn_global_load_lds(
      (const __attribute__((address_space(1))) unsigned int*)g,
      (__attribute__((address_space(3))) unsigned int*)l, 16, 0, 0);
}

// tanh-form GELU: one v_exp_f32, overflow-safe (t=inf -> th=1), max dev ~2e-4
__device__ __forceinline__ float fast_gelu(float v) {
  float u = v * (0.7978845608f + 0.0356774081f * v * v);
  float t = __expf(2.0f * u);
  float th = 1.0f - 2.0f / (t + 1.0f);
  return 0.5f * v * (1.0f + th);
}

// ---------------- router: fp64 logits/softmax/top-2, one wave per token ----------------
__global__ __launch_bounds__(256) void router_kernel(
    const float* __restrict__ x, const float* __restrict__ Wr,
    const float* __restrict__ br, int* __restrict__ topk_e, float* __restrict__ topk_w)
{
  int wave = threadIdx.x >> 6, lane = threadIdx.x & 63;
  int t = blockIdx.x * 4 + wave;
  const float4* xr4 = (const float4*)(x + (size_t)t * DM);
  double acc[NE];
#pragma unroll
  for (int e = 0; e < NE; ++e) acc[e] = 0.0;
#pragma unroll
  for (int it = 0; it < DM / 4 / 64; ++it) {
    int j4 = it * 64 + lane;
    float4 xv = xr4[j4];
    const float* wr = Wr + (size_t)j4 * 4 * NE;
    float xs[4] = {xv.x, xv.y, xv.z, xv.w};
#pragma unroll
    for (int s = 0; s < 4; ++s) {
      double xd = (double)xs[s];
#pragma unroll
      for (int e = 0; e < NE; ++e) acc[e] += xd * (double)wr[s * NE + e];
    }
  }
#pragma unroll
  for (int off = 32; off >= 1; off >>= 1) {
#pragma unroll
    for (int e = 0; e < NE; ++e) acc[e] += __shfl_down(acc[e], off, 64);
  }
  if (lane == 0) {
    double mx = -1e300;
#pragma unroll
    for (int e = 0; e < NE; ++e) { acc[e] += (double)br[e]; if (acc[e] > mx) mx = acc[e]; }
    double p[NE]; double s = 0.0;
#pragma unroll
    for (int e = 0; e < NE; ++e) { p[e] = exp(acc[e] - mx); s += p[e]; }
#pragma unroll
    for (int e = 0; e < NE; ++e) p[e] /= s;
    int e1 = 0;
    for (int e = 1; e < NE; ++e) if (p[e] > p[e1]) e1 = e;           // ties -> lowest idx
    int e2 = (e1 == 0) ? 1 : 0;
    for (int e = 0; e < NE; ++e) { if (e == e1) continue; if (p[e] > p[e2]) e2 = e; }
    double wsum = p[e1] + p[e2]; if (wsum < 1e-9) wsum = 1e-9;
    topk_e[t*2+0] = e1; topk_e[t*2+1] = e2;
    topk_w[t*2+0] = (float)(p[e1] / wsum);
    topk_w[t*2+1] = (float)(p[e2] / wsum);
  }
}

// ---------------- FCFS capacity scan, parallel 3-phase ----------------
__global__ __launch_bounds__(256) void hist_kernel(
    const int* __restrict__ topk_e, int* __restrict__ hist)   // hist[NCHUNK][NE]
{
  __shared__ int wcnt[4][NE];
  int tid = threadIdx.x, lane = tid & 63, wave = tid >> 6;
  int e = topk_e[blockIdx.x * 256 + tid];
#pragma unroll
  for (int ee = 0; ee < NE; ++ee) {
    unsigned long long m = __ballot(e == ee);
    if (lane == 0) wcnt[wave][ee] = __popcll(m);
  }
  __syncthreads();
  if (tid < NE)
    hist[blockIdx.x * NE + tid] = wcnt[0][tid] + wcnt[1][tid] + wcnt[2][tid] + wcnt[3][tid];
}

__global__ __launch_bounds__(64) void prefix_kernel(
    const int* __restrict__ hist, int* __restrict__ base, int* __restrict__ counts)
{
  int e = threadIdx.x;
  if (e >= NE) return;
  int h[NCHUNK];
#pragma unroll
  for (int c = 0; c < NCHUNK; ++c) h[c] = hist[c * NE + e];
  int b = 0;
#pragma unroll
  for (int c = 0; c < NCHUNK; ++c) { base[c * NE + e] = b; b += h[c]; }
  counts[e] = b < CAP ? b : CAP;
}

__global__ __launch_bounds__(256) void assign_kernel(
    const int* __restrict__ topk_e, const int* __restrict__ base,
    int* __restrict__ assign_slot, int* __restrict__ slot_token)
{
  __shared__ int wcnt[4][NE];
  __shared__ int woff[4][NE];
  int tid = threadIdx.x, lane = tid & 63, wave = tid >> 6;
  int gi = blockIdx.x * 256 + tid;
  int e = topk_e[gi];
  int rank = 0;
  unsigned long long lt = (1ull << lane) - 1ull;
#pragma unroll
  for (int ee = 0; ee < NE; ++ee) {
    unsigned long long m = __ballot(e == ee);
    if (e == ee) rank = __popcll(m & lt);
    if (lane == 0) wcnt[wave][ee] = __popcll(m);
  }
  __syncthreads();
  if (tid < NE) {
    int b = base[blockIdx.x * NE + tid];
#pragma unroll
    for (int w = 0; w < 4; ++w) { woff[w][tid] = b; b += wcnt[w][tid]; }
  }
  __syncthreads();
  int pos = woff[wave][e] + rank;
  bool keep = pos < CAP;
  assign_slot[gi] = keep ? (e * CAP + pos) : -1;
  if (keep) slot_token[e * CAP + pos] = gi >> 1;   // K=2
}

// ---------------- fp32 [E][R][C] -> fp16 [E][C][R], 64x64 tiles, 16B I/O both sides ----------------
__global__ __launch_bounds__(256) void transpose_f16(
    const float* __restrict__ in, _Float16* __restrict__ out, int R, int C)
{
  __shared__ float tile[64][65];
  size_t eoff = (size_t)blockIdx.z * R * C;
  const float* src = in + eoff;
  _Float16* dst = out + eoff;
  int r0 = blockIdx.y * 64, c0 = blockIdx.x * 64;
  int t = threadIdx.x;
  int rr = t >> 4, cc = (t & 15) * 4;          // 16 in-rows per pass, float4 each
#pragma unroll
  for (int i = 0; i < 4; ++i) {
    float4 v = *(const float4*)(src + (size_t)(r0 + rr + i*16) * C + (c0 + cc));
    tile[rr + i*16][cc + 0] = v.x; tile[rr + i*16][cc + 1] = v.y;
    tile[rr + i*16][cc + 2] = v.z; tile[rr + i*16][cc + 3] = v.w;
  }
  __syncthreads();
  int oc = t >> 3, orr = (t & 7) * 8;          // 32 out-rows per pass, 8 fp16 each
#pragma unroll
  for (int i = 0; i < 2; ++i) {
    int c = oc + i * 32;
    _Float16 tmp[8];
#pragma unroll
    for (int j = 0; j < 8; ++j) tmp[j] = (_Float16)tile[orr + j][c];
    *(uint4*)(dst + (size_t)(c0 + c) * R + (r0 + orr)) = *(uint4*)tmp;
  }
}

// ---------------- gather kept tokens into [E][CAP][d] fp16 ----------------
__global__ __launch_bounds__(256) void gather_kernel(
    const float* __restrict__ x, const int* __restrict__ slot_token,
    const int* __restrict__ counts, _Float16* __restrict__ xbuf)
{
  int p = blockIdx.x, e = blockIdx.y;
  if (p >= counts[e]) return;
  int tkn = slot_token[e * CAP + p];
  float4 v = ((const float4*)(x + (size_t)tkn * DM))[threadIdx.x];
  _Float16 tmp[4] = {(_Float16)v.x, (_Float16)v.y, (_Float16)v.z, (_Float16)v.w};
  uint2 bits; __builtin_memcpy(&bits, tmp, 8);
  ((uint2*)(xbuf + ((size_t)e * CAP + p) * DM))[threadIdx.x] = bits;
}

// ---------------- fp16 MFMA GEMM, 32x32x16, conflict-free LDS, 4 blocks/CU ----------------
// A: [NE][CAP][K], Bt: [NE][N][K], C: [NE][CAP][N]; tiles past counts[e] early-exit.
// Round-1 2-phase loop (stage -> sync -> compute -> sync) kept verbatim; changes:
// (1) launch_bounds(256,4): 4 blk/CU (32KB LDS x4 = 128 <= 160KB, VGPR<=128) ->
//     GEMM2 2048 eff blocks / 1024 slots = 2.0 exact rounds, GEMM1 4096/1024 = 4.0.
// (2) LDS layout [2 k-halves][128 rows][32 f16]: 64-B row stride + row-swizzle
//     slot = chunk ^ ((r^(r>>2))&3) -- the round-4-validated ZERO-conflict pattern
//     (vs 1.73e7 conflict cycles with the old [128][64] layout).
// (3) bijective XCD remap, bx innermost (round-3/4 validated: FETCH 600->~130MB).
// KSPLIT=2: upper by-half computes k in [K/2,K), partial (no bias) to Cout1.
// 32x32x16 layouts: A/B: m|n=lane&31, k=(lane>>5)*8+j; C/D: col=lane&31,
// row=(reg&3)+8*(reg>>2)+4*(lane>>5).
template <bool GELU, bool OUTF16, int KSPLIT>
__global__ __launch_bounds__(256, 4) void gemm_bt(
    const _Float16* __restrict__ A, const _Float16* __restrict__ Bt,
    const float* __restrict__ bias, void* __restrict__ Cout, void* __restrict__ Cout1,
    const int* __restrict__ counts, int K, int N)
{
  constexpr int BM = 128, BN = 128, BK = 64;
  __shared__ _Float16 As[2][BM * 32];   // [khalf][row][32], 16 KB
  __shared__ _Float16 Bs[2][BN * 32];

  // ---- XCD-aware bijective remap (grid products here are multiples of 8) ----
  int nx = gridDim.x, ny = gridDim.y;
  int w = blockIdx.x + nx * (blockIdx.y + ny * blockIdx.z);
  int nwg = nx * ny * (int)gridDim.z;
  int q = nwg >> 3, r = nwg & 7;
  int xcd = w & 7, idx = w >> 3;
  int L = (xcd < r ? xcd * (q + 1) : r * (q + 1) + (xcd - r) * q) + idx;
  int bx = L % nx; int t1 = L / nx; int by = t1 % ny; int e = t1 / ny;

  int Me = counts[e];
  int split = 0;
  if constexpr (KSPLIT == 2) {
    int nyt = ny >> 1;
    split = by >= nyt;
    if (split) by -= nyt;
  }
  int m0 = by * BM;
  if (m0 >= Me) return;               // capacity padding: skip empty tiles (block-uniform)
  int kbeg = 0, kend = K;
  if constexpr (KSPLIT == 2) { int kh = K >> 1; kbeg = split * kh; kend = kbeg + kh; }

  int tid = threadIdx.x, lane = tid & 63, wave = tid >> 6;
  int wm = wave >> 1, wn = wave & 1;  // 2x2 waves, 64x64 per wave
  const _Float16* Ae = A + ((size_t)e * CAP + m0) * K;
  const _Float16* Be = Bt + ((size_t)e * N + (size_t)bx * BN) * K;
  int srow = lane >> 2, scol = lane & 3;       // staging: 16 rows x 4 chunks per glds16
  int n31 = lane & 31, khalf = lane >> 5;
  int sw4 = (n31 ^ (n31 >> 2)) & 3;            // read-side swizzle (row bases are mult of 32)
  f32x16 acc[2][2] = {};

  for (int k0 = kbeg; k0 < kend; k0 += BK) {
#pragma unroll
    for (int h = 0; h < 2; ++h) {
#pragma unroll
      for (int i = 0; i < 2; ++i) {
        int row = wave * 32 + i * 16 + srow;
        int csw = scol ^ ((row ^ (row >> 2)) & 3);
        size_t goff = (size_t)row * K + (k0 + h * 32 + csw * 8);
        glds16(Ae + goff, (char*)&As[h][0] + (wave * 2048 + i * 1024));
        glds16(Be + goff, (char*)&Bs[h][0] + (wave * 2048 + i * 1024));
      }
    }
    __syncthreads();
    const _Float16* Ab = &As[0][0] + (size_t)(wm * 64 + n31) * 32;
    const _Float16* Bb = &Bs[0][0] + (size_t)(wn * 64 + n31) * 32;
#pragma unroll
    for (int kk = 0; kk < 4; ++kk) {             // 16-k steps
      int c = kk * 2 + khalf;                    // logical 16B chunk 0..7 within row
      int h = c >> 2, sc = c & 3;
      int off = h * (BM * 32) + ((sc ^ sw4) << 3);   // swizzled element offset
      f16x8 a0 = *(const f16x8*)(Ab + off);
      f16x8 a1 = *(const f16x8*)(Ab + off + 32 * 32);
      f16x8 b0 = *(const f16x8*)(Bb + off);
      f16x8 b1 = *(const f16x8*)(Bb + off + 32 * 32);
      acc[0][0] = __builtin_amdgcn_mfma_f32_32x32x16_f16(a0, b0, acc[0][0], 0, 0, 0);
      acc[0][1] = __builtin_amdgcn_mfma_f32_32x32x16_f16(a0, b1, acc[0][1], 0, 0, 0);
      acc[1][0] = __builtin_amdgcn_mfma_f32_32x32x16_f16(a1, b0, acc[1][0], 0, 0, 0);
      acc[1][1] = __builtin_amdgcn_mfma_f32_32x32x16_f16(a1, b1, acc[1][1], 0, 0, 0);
    }
    __syncthreads();
  }

  const float* be = bias + (size_t)e * N;
  float bmul = (split == 0) ? 1.0f : 0.0f;       // bias only in k-split 0
  void* outbase = (split == 0) ? Cout : Cout1;
#pragma unroll
  for (int mi = 0; mi < 2; ++mi) {
#pragma unroll
    for (int reg = 0; reg < 16; ++reg) {
      int row = m0 + wm*64 + mi*32 + 4*khalf + (reg & 3) + 8*(reg >> 2);
      size_t rowoff = ((size_t)e * CAP + row) * N;
#pragma unroll
      for (int ni = 0; ni < 2; ++ni) {
        int col = bx * BN + wn*64 + ni*32 + n31;
        float v = acc[mi][ni][reg] + bmul * be[col];
        if constexpr (GELU) v = fast_gelu(v);
        if constexpr (OUTF16) ((_Float16*)outbase)[rowoff + col] = (_Float16)v;
        else                  ((float*)outbase)[rowoff + col] = v;
      }
    }
  }
}

// ---------------- combine: out[t] = sum_k w_k * (ypart0[slot_k] + ypart1[slot_k]) ----------------
__global__ __launch_bounds__(256) void combine_kernel(
    const float* __restrict__ ybuf0, const float* __restrict__ ybuf1,
    const int* __restrict__ assign_slot, const float* __restrict__ topk_w,
    float* __restrict__ out)
{
  int t = blockIdx.x;
  int s0 = assign_slot[t*2+0], s1 = assign_slot[t*2+1];
  float w0 = topk_w[t*2+0], w1 = topk_w[t*2+1];
  float4 a = {0.f, 0.f, 0.f, 0.f};
  int j = threadIdx.x;
  if (s0 >= 0) {
    float4 y = ((const float4*)(ybuf0 + (size_t)s0 * DM))[j];
    float4 z = ((const float4*)(ybuf1 + (size_t)s0 * DM))[j];
    a.x += w0*(y.x+z.x); a.y += w0*(y.y+z.y); a.z += w0*(y.z+z.z); a.w += w0*(y.w+z.w);
  }
  if (s1 >= 0) {
    float4 y = ((const float4*)(ybuf0 + (size_t)s1 * DM))[j];
    float4 z = ((const float4*)(ybuf1 + (size_t)s1 * DM))[j];
    a.x += w1*(y.x+z.x); a.y += w1*(y.y+z.y); a.z += w1*(y.z+z.z); a.w += w1*(y.w+z.w);
  }
  ((float4*)(out + (size_t)t * DM))[j] = a;
}

extern "C" void kernel_launch(void* const* d_in, const int* in_sizes, int n_in,
                              void* d_out, int out_size, void* d_ws, size_t ws_size,
                              hipStream_t stream)
{
  (void)in_sizes; (void)n_in; (void)out_size; (void)ws_size;
  const float* x  = (const float*)d_in[0];
  const float* Wr = (const float*)d_in[1];
  const float* br = (const float*)d_in[2];
  const float* W1 = (const float*)d_in[3];
  const float* b1 = (const float*)d_in[4];
  const float* W2 = (const float*)d_in[5];
  const float* b2 = (const float*)d_in[6];
  float* out = (float*)d_out;

  char* wsp = (char*)d_ws;
  size_t off = 0;
  auto take = [&](size_t bytes) { char* p = wsp + off; off += (bytes + 255) & ~(size_t)255; return p; };
  // Order matters: W1t and xbuf are adjacent (each size is 256B-aligned already)
  // so their combined 109 MB region can be reused as the 84 MB split-K partial-1
  // buffer for GEMM2 (both are dead once GEMM1 has run). Keeps ws footprint flat.
  _Float16* W2t  = (_Float16*)take((size_t)NE * DM * FF * 2);   // [E][d][f]
  _Float16* W1t  = (_Float16*)take((size_t)NE * FF * DM * 2);   // [E][f][d]
  _Float16* xbuf = (_Float16*)take((size_t)NE * CAP * DM * 2);  // [E][cap][d]
  _Float16* hbuf = (_Float16*)take((size_t)NE * CAP * FF * 2);  // [E][cap][f]
  float*    ybuf = (float*)take((size_t)NE * CAP * DM * 4);     // [E][cap][d] k-split partial 0
  float*    ybuf1 = (float*)W1t;  // k-split partial 1 aliases (dead) W1t+xbuf: 109MB >= 84MB
  int*   topk_e      = (int*)take((size_t)T_TOK * KTOP * 4);
  float* topk_w      = (float*)take((size_t)T_TOK * KTOP * 4);
  int*   assign_slot = (int*)take((size_t)T_TOK * KTOP * 4);
  int*   slot_token  = (int*)take((size_t)NE * CAP * 4);
  int*   counts      = (int*)take((size_t)NE * 4);
  int*   hist        = (int*)take((size_t)NCHUNK * NE * 4);
  int*   cbase       = (int*)take((size_t)NCHUNK * NE * 4);

  router_kernel<<<T_TOK / 4, 256, 0, stream>>>(x, Wr, br, topk_e, topk_w);
  hist_kernel<<<NCHUNK, 256, 0, stream>>>(topk_e, hist);
  prefix_kernel<<<1, 64, 0, stream>>>(hist, cbase, counts);
  assign_kernel<<<NCHUNK, 256, 0, stream>>>(topk_e, cbase, assign_slot, slot_token);
  transpose_f16<<<dim3(FF/64, DM/64, NE), 256, 0, stream>>>(W1, W1t, DM, FF);
  transpose_f16<<<dim3(DM/64, FF/64, NE), 256, 0, stream>>>(W2, W2t, FF, DM);
  gather_kernel<<<dim3(CAP, NE), 256, 0, stream>>>(x, slot_token, counts, xbuf);
  gemm_bt<true,  true,  1><<<dim3(FF/128, CAP/128, NE), 256, 0, stream>>>(
      xbuf, W1t, b1, (void*)hbuf, nullptr, counts, DM, FF);
  gemm_bt<false, false, 2><<<dim3(DM/128, (CAP/128)*2, NE), 256, 0, stream>>>(
      hbuf, W2t, b2, (void*)ybuf, (void*)ybuf1, counts, FF, DM);
  combine_kernel<<<T_TOK, 256, 0, stream>>>(ybuf, ybuf1, assign_slot, topk_w, out);
}